// Round 2
// baseline (172.693 us; speedup 1.0000x reference)
//
#include <hip/hip_runtime.h>

#define NN 100000
#define NE 1600000
#define TT 12
#define HH 32
#define NB 391          // coarse buckets of 256 nodes (node bucket = d >> 8)
#define BSH 8
#define GCS 16          // gcursor stride (ints) = one 64B line per cursor
#define CHUNK 4096      // edges per scatter block
#define SORTCAP 4800    // records per sort block (mean 4096, sigma 64 -> +11 sigma)
#define LOG2E 1.4426950408889634f

// ---------------- workspace layout (4-byte units), ~14.0 MB ----------------
// [0, 400)             : bstart[392]
// [400, 800)           : cnt[391]            (zeroed by one memset with deg)
// [800, 100800)        : deg[100000] (float) (zeroed by same memset)
// [100800, 107056)     : gcursor (x16 padded)
// [107056, 207072)     : nodebase[100001]
// [207072, 307072)     : dinv (float)
// [307072, 3507072)    : rec (int2[NE]); byte off 1228288 % 8 == 0
// [3507072, 3507216)   : P params: Az[32],Bz[32],Ah2[32],Bh2[32],probs[12]
//                        (all pre-scaled by log2(e) for raw v_exp_f32)

// Bucket histogram + per-node weighted degree in ONE pass over edges.
// deg via fire-and-forget global float atomics (random over 400KB -> L2-resident).
__global__ __launch_bounds__(256) void k_bhist(const int* __restrict__ ei,
                                               const float* __restrict__ ew,
                                               int* __restrict__ cnt,
                                               float* __restrict__ deg) {
    __shared__ int h[NB];
    int b = blockIdx.x, t = threadIdx.x;
    for (int j = t; j < NB; j += 256) h[j] = 0;
    __syncthreads();
    const int EPB = NE / 512;  // 3125
    int e0 = b * EPB;
    for (int k = t; k < EPB; k += 256) {
        int d = ei[NE + e0 + k];
        atomicAdd(&h[d >> BSH], 1);
        atomicAdd(&deg[d], ew[e0 + k]);
    }
    __syncthreads();
    for (int j = t; j < NB; j += 256) if (h[j]) atomicAdd(&cnt[j], h[j]);
}

// Grid 198: block 0 = bucket scan; blocks 1..196 = dinv; block 197 = gate params.
__global__ __launch_bounds__(512) void k_bscan(const int* __restrict__ cnt,
                                               int* __restrict__ bstart,
                                               int* __restrict__ gcursor,
                                               const float* __restrict__ deg,
                                               float* __restrict__ dinv,
                                               const float* __restrict__ czw, const float* __restrict__ czb,
                                               const float* __restrict__ lzw, const float* __restrict__ lzb,
                                               const float* __restrict__ chw, const float* __restrict__ chb,
                                               const float* __restrict__ lhw, const float* __restrict__ lhb,
                                               const float* __restrict__ att, float* __restrict__ P) {
    int blk = blockIdx.x, t = threadIdx.x;
    if (blk == 0) {
        __shared__ int sc[512];
        int v = (t < NB) ? cnt[t] : 0;
        sc[t] = v;
        __syncthreads();
        for (int o = 1; o < 512; o <<= 1) {
            int add = (t >= o) ? sc[t - o] : 0;
            __syncthreads();
            sc[t] += add;
            __syncthreads();
        }
        if (t < NB) {
            int e = sc[t] - v;  // exclusive prefix
            bstart[t] = e;
            gcursor[t * GCS] = e;
        }
        if (t == 0) bstart[NB] = NE;
    } else if (blk <= 196) {
        int n = (blk - 1) * 512 + t;
        if (n < NN) dinv[n] = rsqrtf(1.0f + deg[n]);  // +1 = self loop
    } else {
        int j = t;
        if (j < HH) {
            float az = 0.f, bz = 0.f, ah = 0.f, bh = 0.f;
            for (int k = 0; k < HH; ++k) {
                float lz = lzw[k * HH + j];
                float lh = lhw[k * HH + j];
                az = fmaf(czw[k], lz, az);
                bz = fmaf(czb[k], lz, bz);
                ah = fmaf(chw[k], lh, ah);
                bh = fmaf(chb[k], lh, bh);
            }
            // pre-scale by log2e so the hot loop uses raw v_exp_f32 (2^x)
            P[j]        = az * LOG2E;
            P[HH + j]   = (bz + lzb[j]) * LOG2E;
            P[2*HH + j] = 2.0f * LOG2E * ah;          // tanh(x) = f(2^(2x*log2e))
            P[3*HH + j] = 2.0f * LOG2E * (bh + lhb[j]);
        }
        if (t == 0) {
            float m = -1e30f;
            for (int q = 0; q < TT; ++q) m = fmaxf(m, att[q]);
            float ex[TT]; float s = 0.f;
            for (int q = 0; q < TT; ++q) { ex[q] = expf(att[q] - m); s += ex[q]; }
            for (int q = 0; q < TT; ++q) P[4*HH + q] = ex[q] / s;
        }
    }
}

// Chunk-local counting sort; now folds the FULL edge coefficient
// w = ew * dinv[src] * dinv[dst] into rec.y (dinv complete after k_bscan),
// so k_fused's inner loop has no dinv loads at all.
__global__ __launch_bounds__(512) void k_scatter(const int* __restrict__ ei,
                                                 const float* __restrict__ ew,
                                                 const float* __restrict__ dinv,
                                                 int* __restrict__ gcursor,
                                                 int2* __restrict__ rec) {
    __shared__ int2 cbuf[CHUNK];                 // 32 KB
    __shared__ unsigned short bkt[CHUNK];        // 8 KB
    __shared__ int sc[512];
    __shared__ int cnt[NB], off[NB], cur[NB], gb[NB];
    int t = threadIdx.x;
    int base = blockIdx.x * CHUNK;
    int m = min(CHUNK, NE - base);
    for (int j = t; j < NB; j += 512) { cnt[j] = 0; cur[j] = 0; }
    __syncthreads();
    int dsts[8], srcs[8]; float wts[8];
#pragma unroll
    for (int i = 0; i < 8; ++i) {
        int k = t + i * 512;
        if (k < m) {
            int e = base + k;
            dsts[i] = ei[NE + e]; srcs[i] = ei[e];
            wts[i] = ew[e] * dinv[srcs[i]] * dinv[dsts[i]];  // fully folded coeff
            atomicAdd(&cnt[dsts[i] >> BSH], 1);
        }
    }
    __syncthreads();
    int v = (t < NB) ? cnt[t] : 0;
    sc[t] = v;
    __syncthreads();
    for (int o = 1; o < 512; o <<= 1) {
        int add = (t >= o) ? sc[t - o] : 0;
        __syncthreads();
        sc[t] += add;
        __syncthreads();
    }
    if (t < NB) {
        off[t] = sc[t] - v;
        gb[t] = v ? atomicAdd(&gcursor[t * GCS], v) : 0;
    }
    __syncthreads();
#pragma unroll
    for (int i = 0; i < 8; ++i) {
        int k = t + i * 512;
        if (k < m) {
            int b = dsts[i] >> BSH;
            int p = off[b] + atomicAdd(&cur[b], 1);
            // src in bits 0..16 (100000 < 2^17), node-local dst (d&255) in 17..24
            cbuf[p] = make_int2(srcs[i] | ((dsts[i] & 255) << 17), __float_as_int(wts[i]));
            bkt[p] = (unsigned short)b;
        }
    }
    __syncthreads();
    for (int k = t; k < m; k += 512) {
        int b = bkt[k];
        rec[gb[b] + (k - off[b])] = cbuf[k];
    }
}

// One block = one coarse bucket = 256 nodes. Pure integer counting sort now
// (no wsum/dinv work here anymore); 512 threads for 2x the TLP.
__global__ __launch_bounds__(512) void k_sort(const int* __restrict__ bstart,
                                              int2* __restrict__ rec,
                                              int* __restrict__ nodebase) {
    __shared__ int2 buf[SORTCAP];                // 37.5 KB
    __shared__ int cnt[256], cur[256], sc[512];
    int blk = blockIdx.x, t = threadIdx.x;
    int g0 = bstart[blk], g1 = bstart[blk + 1];
    int m = min(g1 - g0, SORTCAP);
    if (t < 256) cnt[t] = 0;
    __syncthreads();
    for (int k = t; k < m; k += 512) {
        int2 r = rec[g0 + k];
        buf[k] = r;
        atomicAdd(&cnt[(r.x >> 17) & 255], 1);
    }
    __syncthreads();
    int v = (t < 256) ? cnt[t] : 0;
    sc[t] = v;
    __syncthreads();
    for (int o = 1; o < 256; o <<= 1) {
        int add = (t >= o) ? sc[t - o] : 0;
        __syncthreads();
        sc[t] += add;
        __syncthreads();
    }
    if (t < 256) {
        int e = sc[t] - v;  // exclusive prefix
        cur[t] = e;
        int n = (blk << BSH) + t;
        if (n < NN) nodebase[n] = g0 + e;
    }
    if (blk == NB - 1 && t == 0) nodebase[NN] = NE;
    __syncthreads();
    for (int k = t; k < m; k += 512) {
        int2 r = buf[k];
        int loc = (r.x >> 17) & 255;
        int p = atomicAdd(&cur[loc], 1);
        rec[g0 + p] = make_int2(r.x & 0x1FFFF, r.y);
    }
}

// 8 lanes per node; inner loop is now rec -> x only (coefficient fully folded).
// Epilogue uses raw exp2 (params pre-scaled by log2e) and the minimal clamp:
// only eh must stay finite (eh=inf would give inf*0=NaN); ez overflow is
// graceful (den=inf -> rcp=0 -> contribution 0 == the correct sigmoid limit).
__global__ __launch_bounds__(256) void k_fused(const float* __restrict__ x,
                                               const int* __restrict__ nodebase,
                                               const int2* __restrict__ rec,
                                               const float* __restrict__ dinv,
                                               const float* __restrict__ P,
                                               const float* __restrict__ hw,
                                               const float* __restrict__ hb,
                                               float* __restrict__ out) {
    int g = blockIdx.x * 256 + threadIdx.x;
    int n = g >> 3, sub = g & 7;   // NN*8 = 800000 = 3125*256 exactly, no guard
    float a[TT];
#pragma unroll
    for (int q = 0; q < TT; ++q) a[q] = 0.f;
    if (sub == 0) {
        float di = dinv[n];
        float c = di * di;  // self-loop norm
        const float4* xr = (const float4*)(x + (long)n * TT);
#pragma unroll
        for (int q = 0; q < 3; ++q) {
            float4 v = xr[q];
            a[q*4+0] = c * v.x; a[q*4+1] = c * v.y;
            a[q*4+2] = c * v.z; a[q*4+3] = c * v.w;
        }
    }
    int k0 = nodebase[n], k1 = nodebase[n + 1];
    for (int k = k0 + sub; k < k1; k += 8) {
        int2 r = rec[k];
        float c = __int_as_float(r.y);  // = ew * dinv[src] * dinv[dst]
        const float4* xs = (const float4*)(x + (long)r.x * TT);
        float4 v0 = xs[0], v1 = xs[1], v2 = xs[2];
        a[0]  = fmaf(c, v0.x, a[0]);  a[1]  = fmaf(c, v0.y, a[1]);
        a[2]  = fmaf(c, v0.z, a[2]);  a[3]  = fmaf(c, v0.w, a[3]);
        a[4]  = fmaf(c, v1.x, a[4]);  a[5]  = fmaf(c, v1.y, a[5]);
        a[6]  = fmaf(c, v1.z, a[6]);  a[7]  = fmaf(c, v1.w, a[7]);
        a[8]  = fmaf(c, v2.x, a[8]);  a[9]  = fmaf(c, v2.y, a[9]);
        a[10] = fmaf(c, v2.z, a[10]); a[11] = fmaf(c, v2.w, a[11]);
    }
    // tree-reduce the 12 accumulators across the 8 lanes of this node
#pragma unroll
    for (int q = 0; q < TT; ++q) {
        float v = a[q];
        v += __shfl_xor(v, 1);
        v += __shfl_xor(v, 2);
        v += __shfl_xor(v, 4);
        a[q] = v;
    }
    // --- epilogue: gates + attention + head, 4 hidden channels per lane ---
    float p[TT];
#pragma unroll
    for (int q = 0; q < TT; ++q) p[q] = P[4*HH + q];
    float o = 0.f;
#pragma unroll
    for (int jj = 0; jj < 4; ++jj) {
        int j = (jj << 3) + sub;
        float Az = P[j], Bz = P[HH + j], Ah2 = P[2*HH + j], Bh2 = P[3*HH + j];
        float w = hw[j];
        float acc = 0.f;
#pragma unroll
        for (int q = 0; q < TT; ++q) {
            float xz = fmaf(a[q], Az, Bz);                   // log2-domain
            float xh = fminf(fmaf(a[q], Ah2, Bh2), 115.f);   // keep eh finite
            float ez = __builtin_amdgcn_exp2f(xz);  // e^orig_xz
            float eh = __builtin_amdgcn_exp2f(xh);  // e^(2*orig_xh)
            float den = (1.f + ez) * (eh + 1.f);
            float num = eh - 1.f;
            acc = fmaf(p[q] * num, __builtin_amdgcn_rcpf(den), acc);
        }
        o = fmaf(fmaxf(acc, 0.f), w, o);
    }
    o += __shfl_xor(o, 1);
    o += __shfl_xor(o, 2);
    o += __shfl_xor(o, 4);
    if (sub == 0) out[n] = o + hb[0];
}

extern "C" void kernel_launch(void* const* d_in, const int* in_sizes, int n_in,
                              void* d_out, int out_size, void* d_ws, size_t ws_size,
                              hipStream_t stream) {
    const float* x    = (const float*)d_in[0];
    const int*   ei   = (const int*)d_in[1];
    const float* ew   = (const float*)d_in[2];
    const float* att  = (const float*)d_in[3];
    const float* czw  = (const float*)d_in[4];
    const float* czb  = (const float*)d_in[5];
    const float* lzw  = (const float*)d_in[6];
    const float* lzb  = (const float*)d_in[7];
    // conv_r / lin_r (d_in[8..11]) are mathematically dead: H=0 -> H*R=0, Z*H=0.
    const float* chw  = (const float*)d_in[12];
    const float* chb  = (const float*)d_in[13];
    const float* lhw  = (const float*)d_in[14];
    const float* lhb  = (const float*)d_in[15];
    const float* hw   = (const float*)d_in[16];
    const float* hb   = (const float*)d_in[17];
    float* out = (float*)d_out;

    int*  ws32     = (int*)d_ws;
    int*  bstart   = ws32;                     // 392 (pad to 400)
    int*  cnt      = ws32 + 400;               // 391 (pad to 400)
    float* deg     = (float*)(ws32 + 800);     // 100000
    int*  gcursor  = ws32 + 100800;            // NB*GCS = 6256
    int*  nodebase = ws32 + 107056;            // 100001 (pad to 100016)
    float* dinv    = (float*)(ws32 + 207072);  // NN
    int2* rec      = (int2*)(ws32 + 307072);   // NE int2; byte off 1228288 % 8 == 0
    float* P       = (float*)(ws32 + 3507072); // 144

    // one memset covers cnt[391] + pad + deg[100000] (contiguous region)
    hipMemsetAsync(ws32 + 400, 0, (size_t)(100800 - 400) * 4, stream);
    k_bhist<<<512, 256, 0, stream>>>(ei, ew, cnt, deg);
    k_bscan<<<198, 512, 0, stream>>>(cnt, bstart, gcursor, deg, dinv,
                                     czw, czb, lzw, lzb, chw, chb, lhw, lhb, att, P);
    k_scatter<<<(NE + CHUNK - 1) / CHUNK, 512, 0, stream>>>(ei, ew, dinv, gcursor, rec);
    k_sort<<<NB, 512, 0, stream>>>(bstart, rec, nodebase);
    k_fused<<<(NN * 8) / 256, 256, 0, stream>>>(x, nodebase, rec, dinv, P, hw, hb, out);
}

// Round 3
// 103.475 us; speedup vs baseline: 1.6689x; 1.6689x over previous
//
#include <hip/hip_runtime.h>

#define NN 100000
#define NE 1600000
#define TT 12
#define HH 32
#define NB 391          // coarse buckets of 256 nodes (node bucket = d >> 8)
#define BSH 8
#define GCS 16          // gcursor stride (ints) = one 64B line per cursor
#define CHUNK 4096      // edges per scatter block
#define SORTCAP 4800    // records per sort block (mean 4096, sigma 64 -> +11 sigma)
#define LOG2E 1.4426950408889634f

// ---------------- workspace layout (4-byte units), ~13.6 MB ----------------
// [0, 400)             : bstart[392]
// [400, 800)           : cnt[391]      (zeroed by memset)
// [800, 816)           : done flag     (zeroed by same memset)
// [816, 7072)          : gcursor (x16 padded)
// [7072, 107088)       : nodebase[100001]
// [107088, 207088)     : dinv (float)
// [207088, 3407088)    : rec (int2[NE]); byte off 828352 % 8 == 0
// [3407088, 3407232)   : P params: Az[32],Bz[32],Ah2[32],Bh2[32],probs[12]
//                        (gate params pre-scaled by log2e for raw v_exp_f32)

// Bucket histogram; the LAST block to finish (global done counter) then does
// the bucket scan + gate-param folding in the same launch (saves 2 dispatches).
// NOTE: per-edge GLOBAL float atomics are catastrophic on gfx950 (R2: 90us,
// WRITE_SIZE == 1.6M x 32B -> uncached fabric writes). Histogram uses LDS
// atomics + one int atomic per (block, nonempty bucket) only.
__global__ __launch_bounds__(256) void k_pre(const int* __restrict__ ei,
                                             int* __restrict__ cnt,
                                             int* __restrict__ done,
                                             int* __restrict__ bstart,
                                             int* __restrict__ gcursor,
                                             const float* __restrict__ czw, const float* __restrict__ czb,
                                             const float* __restrict__ lzw, const float* __restrict__ lzb,
                                             const float* __restrict__ chw, const float* __restrict__ chb,
                                             const float* __restrict__ lhw, const float* __restrict__ lhb,
                                             const float* __restrict__ att, float* __restrict__ P) {
    __shared__ int h[NB];
    __shared__ int lastFlag;
    int b = blockIdx.x, t = threadIdx.x;
    for (int j = t; j < NB; j += 256) h[j] = 0;
    __syncthreads();
    const int EPB = NE / 256;  // 6250
    int e0 = b * EPB;
    for (int k = t; k < EPB; k += 256) atomicAdd(&h[ei[NE + e0 + k] >> BSH], 1);
    __syncthreads();
    for (int j = t; j < NB; j += 256) if (h[j]) atomicAdd(&cnt[j], h[j]);
    // ---- last-done block performs the scan + params ----
    if (t == 0) {
        __threadfence();
        int r = atomicAdd(done, 1);
        lastFlag = (r == (int)gridDim.x - 1);
    }
    __syncthreads();
    if (!lastFlag) return;
    // each thread owns 2 consecutive buckets (512 >= 391)
    int j0 = 2 * t;
    int c0 = 0, c1 = 0;
    if (j0 < NB)     c0 = atomicAdd(&cnt[j0], 0);      // device-scope load (skip stale L1)
    if (j0 + 1 < NB) c1 = atomicAdd(&cnt[j0 + 1], 0);
    int s = c0 + c1;
    __syncthreads();           // h[] reuse as scan buffer
    h[t] = s;
    __syncthreads();
    for (int o = 1; o < 256; o <<= 1) {
        int add = (t >= o) ? h[t - o] : 0;
        __syncthreads();
        h[t] += add;
        __syncthreads();
    }
    int e = h[t] - s;  // exclusive prefix over thread-pairs
    if (j0 < NB)     { bstart[j0] = e;     gcursor[j0 * GCS] = e; }
    e += c0;
    if (j0 + 1 < NB) { bstart[j0 + 1] = e; gcursor[(j0 + 1) * GCS] = e; }
    if (t == 0) bstart[NB] = NE;
    // ---- gate params (threads 0..31) ----
    if (t < HH) {
        int j = t;
        float az = 0.f, bz = 0.f, ah = 0.f, bh = 0.f;
        for (int k = 0; k < HH; ++k) {
            float lz = lzw[k * HH + j];
            float lh = lhw[k * HH + j];
            az = fmaf(czw[k], lz, az);
            bz = fmaf(czb[k], lz, bz);
            ah = fmaf(chw[k], lh, ah);
            bh = fmaf(chb[k], lh, bh);
        }
        // pre-scale by log2e so the hot loop uses raw v_exp_f32 (2^x)
        P[j]        = az * LOG2E;
        P[HH + j]   = (bz + lzb[j]) * LOG2E;
        P[2*HH + j] = 2.0f * LOG2E * ah;          // tanh(x) = f(2^(2x*log2e))
        P[3*HH + j] = 2.0f * LOG2E * (bh + lhb[j]);
    }
    if (t == 0) {
        float m = -1e30f;
        for (int q = 0; q < TT; ++q) m = fmaxf(m, att[q]);
        float ex[TT]; float ssum = 0.f;
        for (int q = 0; q < TT; ++q) { ex[q] = expf(att[q] - m); ssum += ex[q]; }
        for (int q = 0; q < TT; ++q) P[4*HH + q] = ex[q] / ssum;
    }
}

// Chunk-local counting sort: bin 4096 edges in LDS, reserve per-bucket global
// runs (1 atomic per non-empty bucket), stream out so each cache line is
// written by one wave in one burst. rec.y = raw ew (dinv folded later).
__global__ __launch_bounds__(512) void k_scatter(const int* __restrict__ ei,
                                                 const float* __restrict__ ew,
                                                 int* __restrict__ gcursor,
                                                 int2* __restrict__ rec) {
    __shared__ int2 cbuf[CHUNK];                 // 32 KB
    __shared__ unsigned short bkt[CHUNK];        // 8 KB
    __shared__ int sc[512];
    __shared__ int cnt[NB], off[NB], cur[NB], gb[NB];
    int t = threadIdx.x;
    int base = blockIdx.x * CHUNK;
    int m = min(CHUNK, NE - base);
    for (int j = t; j < NB; j += 512) { cnt[j] = 0; cur[j] = 0; }
    __syncthreads();
    int dsts[8], srcs[8]; float ews[8];
#pragma unroll
    for (int i = 0; i < 8; ++i) {
        int k = t + i * 512;
        if (k < m) {
            int e = base + k;
            dsts[i] = ei[NE + e]; srcs[i] = ei[e]; ews[i] = ew[e];
            atomicAdd(&cnt[dsts[i] >> BSH], 1);
        }
    }
    __syncthreads();
    int v = (t < NB) ? cnt[t] : 0;
    sc[t] = v;
    __syncthreads();
    for (int o = 1; o < 512; o <<= 1) {
        int add = (t >= o) ? sc[t - o] : 0;
        __syncthreads();
        sc[t] += add;
        __syncthreads();
    }
    if (t < NB) {
        off[t] = sc[t] - v;
        gb[t] = v ? atomicAdd(&gcursor[t * GCS], v) : 0;
    }
    __syncthreads();
#pragma unroll
    for (int i = 0; i < 8; ++i) {
        int k = t + i * 512;
        if (k < m) {
            int b = dsts[i] >> BSH;
            int p = off[b] + atomicAdd(&cur[b], 1);
            // src in bits 0..16 (100000 < 2^17), node-local dst (d&255) in 17..24
            cbuf[p] = make_int2(srcs[i] | ((dsts[i] & 255) << 17), __float_as_int(ews[i]));
            bkt[p] = (unsigned short)b;
        }
    }
    __syncthreads();
    for (int k = t; k < m; k += 512) {
        int b = bkt[k];
        rec[gb[b] + (k - off[b])] = cbuf[k];
    }
}

// One block = one coarse bucket = 256 nodes. In-place sort to exact per-node
// order; computes dinv + nodebase via LDS float atomics (fast, unlike global);
// pre-scales weight by dinv[dst]. 512 threads for latency hiding (grid is
// only 1.5 blocks/CU, so more waves per block is the only TLP lever).
__global__ __launch_bounds__(512) void k_sort(const int* __restrict__ bstart,
                                              int2* __restrict__ rec,
                                              int* __restrict__ nodebase,
                                              float* __restrict__ dinv) {
    __shared__ int2 buf[SORTCAP];                // 37.5 KB
    __shared__ int cnt[256], cur[256], sc[512];
    __shared__ float wsum[256], dvs[256];
    int blk = blockIdx.x, t = threadIdx.x;
    int g0 = bstart[blk], g1 = bstart[blk + 1];
    int m = min(g1 - g0, SORTCAP);
    if (t < 256) { cnt[t] = 0; wsum[t] = 0.f; }
    __syncthreads();
    for (int k = t; k < m; k += 512) {
        int2 r = rec[g0 + k];
        buf[k] = r;
        int loc = (r.x >> 17) & 255;
        atomicAdd(&cnt[loc], 1);
        atomicAdd(&wsum[loc], __int_as_float(r.y));
    }
    __syncthreads();
    int v = (t < 256) ? cnt[t] : 0;
    sc[t] = v;
    __syncthreads();
    for (int o = 1; o < 256; o <<= 1) {
        int add = (t >= o) ? sc[t - o] : 0;
        __syncthreads();
        sc[t] += add;
        __syncthreads();
    }
    if (t < 256) {
        int e = sc[t] - v;  // exclusive prefix
        cur[t] = e;
        float dv = rsqrtf(1.0f + wsum[t]);  // +1 = self loop
        dvs[t] = dv;
        int n = (blk << BSH) + t;
        if (n < NN) { dinv[n] = dv; nodebase[n] = g0 + e; }
    }
    if (blk == NB - 1 && t == 0) nodebase[NN] = NE;
    __syncthreads();
    for (int k = t; k < m; k += 512) {
        int2 r = buf[k];
        int loc = (r.x >> 17) & 255;
        int p = atomicAdd(&cur[loc], 1);
        float w2 = __int_as_float(r.y) * dvs[loc];  // fold dinv[dst] into weight
        rec[g0 + p] = make_int2(r.x & 0x1FFFF, __float_as_int(w2));
    }
}

// 8 lanes per node (coalesced rec reads, 3-level shfl_xor reduce).
// 512-thread blocks: 1563 blocks = 6.1/CU, 4 resident blocks = 32 waves/CU
// (R1 at 256-thread blocks averaged only 17/32 waves resident; waves are
// ~90% memory-stalled, so residency is the lever).
// Epilogue in exp2 domain (P pre-scaled by log2e); only the tanh exponent
// needs an upper clamp (eh=inf would give inf*0=NaN; ez overflow is graceful:
// den=inf -> rcp=0 -> correct sigmoid limit).
__global__ __launch_bounds__(512) void k_fused(const float* __restrict__ x,
                                               const int* __restrict__ nodebase,
                                               const int2* __restrict__ rec,
                                               const float* __restrict__ dinv,
                                               const float* __restrict__ P,
                                               const float* __restrict__ hw,
                                               const float* __restrict__ hb,
                                               float* __restrict__ out) {
    int g = blockIdx.x * 512 + threadIdx.x;
    int n = g >> 3, sub = g & 7;
    if (n >= NN) return;
    float a[TT];
#pragma unroll
    for (int q = 0; q < TT; ++q) a[q] = 0.f;
    if (sub == 0) {
        float di = dinv[n];
        float c = di * di;  // self-loop norm
        const float4* xr = (const float4*)(x + (long)n * TT);
#pragma unroll
        for (int q = 0; q < 3; ++q) {
            float4 v = xr[q];
            a[q*4+0] = c * v.x; a[q*4+1] = c * v.y;
            a[q*4+2] = c * v.z; a[q*4+3] = c * v.w;
        }
    }
    int k0 = nodebase[n], k1 = nodebase[n + 1];
    for (int k = k0 + sub; k < k1; k += 8) {
        int2 r = rec[k];
        int s = r.x;
        float c = dinv[s] * __int_as_float(r.y);  // w already scaled by dinv[dst]
        const float4* xs = (const float4*)(x + (long)s * TT);
        float4 v0 = xs[0], v1 = xs[1], v2 = xs[2];
        a[0]  = fmaf(c, v0.x, a[0]);  a[1]  = fmaf(c, v0.y, a[1]);
        a[2]  = fmaf(c, v0.z, a[2]);  a[3]  = fmaf(c, v0.w, a[3]);
        a[4]  = fmaf(c, v1.x, a[4]);  a[5]  = fmaf(c, v1.y, a[5]);
        a[6]  = fmaf(c, v1.z, a[6]);  a[7]  = fmaf(c, v1.w, a[7]);
        a[8]  = fmaf(c, v2.x, a[8]);  a[9]  = fmaf(c, v2.y, a[9]);
        a[10] = fmaf(c, v2.z, a[10]); a[11] = fmaf(c, v2.w, a[11]);
    }
    // tree-reduce the 12 accumulators across the 8 lanes of this node
#pragma unroll
    for (int q = 0; q < TT; ++q) {
        float v = a[q];
        v += __shfl_xor(v, 1);
        v += __shfl_xor(v, 2);
        v += __shfl_xor(v, 4);
        a[q] = v;
    }
    // --- epilogue: gates + attention + head, 4 hidden channels per lane ---
    float p[TT];
#pragma unroll
    for (int q = 0; q < TT; ++q) p[q] = P[4*HH + q];
    float o = 0.f;
#pragma unroll
    for (int jj = 0; jj < 4; ++jj) {
        int j = (jj << 3) + sub;
        float Az = P[j], Bz = P[HH + j], Ah2 = P[2*HH + j], Bh2 = P[3*HH + j];
        float w = hw[j];
        float acc = 0.f;
#pragma unroll
        for (int q = 0; q < TT; ++q) {
            float xz = fmaf(a[q], Az, Bz);                   // log2-domain
            float xh = fminf(fmaf(a[q], Ah2, Bh2), 115.f);   // keep eh finite
            float ez = __builtin_amdgcn_exp2f(xz);  // e^orig_xz
            float eh = __builtin_amdgcn_exp2f(xh);  // e^(2*orig_xh)
            float den = (1.f + ez) * (eh + 1.f);
            float num = eh - 1.f;
            acc = fmaf(p[q] * num, __builtin_amdgcn_rcpf(den), acc);
        }
        o = fmaf(fmaxf(acc, 0.f), w, o);
    }
    o += __shfl_xor(o, 1);
    o += __shfl_xor(o, 2);
    o += __shfl_xor(o, 4);
    if (sub == 0) out[n] = o + hb[0];
}

extern "C" void kernel_launch(void* const* d_in, const int* in_sizes, int n_in,
                              void* d_out, int out_size, void* d_ws, size_t ws_size,
                              hipStream_t stream) {
    const float* x    = (const float*)d_in[0];
    const int*   ei   = (const int*)d_in[1];
    const float* ew   = (const float*)d_in[2];
    const float* att  = (const float*)d_in[3];
    const float* czw  = (const float*)d_in[4];
    const float* czb  = (const float*)d_in[5];
    const float* lzw  = (const float*)d_in[6];
    const float* lzb  = (const float*)d_in[7];
    // conv_r / lin_r (d_in[8..11]) are mathematically dead: H=0 -> H*R=0, Z*H=0.
    const float* chw  = (const float*)d_in[12];
    const float* chb  = (const float*)d_in[13];
    const float* lhw  = (const float*)d_in[14];
    const float* lhb  = (const float*)d_in[15];
    const float* hw   = (const float*)d_in[16];
    const float* hb   = (const float*)d_in[17];
    float* out = (float*)d_out;

    int*  ws32     = (int*)d_ws;
    int*  bstart   = ws32;                     // 392 (pad to 400)
    int*  cnt      = ws32 + 400;               // 391 (pad to 400)
    int*  done     = ws32 + 800;               // 1 (pad to 16)
    int*  gcursor  = ws32 + 816;               // NB*GCS = 6256
    int*  nodebase = ws32 + 7072;              // 100001 (pad to 100016)
    float* dinv    = (float*)(ws32 + 107088);  // NN
    int2* rec      = (int2*)(ws32 + 207088);   // NE int2; byte off 828352 % 8 == 0
    float* P       = (float*)(ws32 + 3407088); // 144

    hipMemsetAsync(ws32 + 400, 0, (size_t)(816 - 400) * 4, stream);  // cnt + done
    k_pre<<<256, 256, 0, stream>>>(ei, cnt, done, bstart, gcursor,
                                   czw, czb, lzw, lzb, chw, chb, lhw, lhb, att, P);
    k_scatter<<<(NE + CHUNK - 1) / CHUNK, 512, 0, stream>>>(ei, ew, gcursor, rec);
    k_sort<<<NB, 512, 0, stream>>>(bstart, rec, nodebase, dinv);
    k_fused<<<(NN * 8 + 511) / 512, 512, 0, stream>>>(x, nodebase, rec, dinv, P, hw, hb, out);
}

// Round 4
// 100.268 us; speedup vs baseline: 1.7223x; 1.0320x over previous
//
#include <hip/hip_runtime.h>

#define NN 100000
#define NE 1600000
#define TT 12
#define HH 32
#define NB 391          // coarse buckets of 256 nodes (node bucket = d >> 8)
#define BSH 8
#define GCS 16          // gcursor stride (ints) = one 64B line per cursor
#define CHUNK 4096      // edges per scatter block
#define SORTCAP 4800    // records per sort block (mean 4096, sigma 64 -> +11 sigma)
#define LOG2E 1.4426950408889634f

// ---------------- workspace layout (4-byte units), ~20.0 MB ----------------
// [0, 400)             : bstart[392]
// [400, 800)           : cnt[391]      (zeroed by memset)
// [800, 816)           : done flag     (zeroed by same memset)
// [816, 7072)          : gcursor (x16 padded)
// [7072, 107088)       : nodebase[100001]
// [107088, 207088)     : dinv (float)
// [207104, 1807104)    : xp (float[NN][16]) = dinv[n]*x[n], 64B-aligned rows
// [1807104, 5007104)   : rec (int2[NE]); byte off 7228416 % 8 == 0
// [5007104, 5007248)   : P params: Az[32],Bz[32],Ah2[32],Bh2[32],probs[12]
//                        (gate params pre-scaled by log2e for raw v_exp_f32)

// Bucket histogram; the LAST block to finish (global done counter) then does
// the bucket scan + gate-param folding in the same launch.
// NOTE: per-edge GLOBAL float atomics are catastrophic on gfx950 (R2: 90us,
// WRITE_SIZE == 1.6M x 32B -> uncached fabric writes). LDS atomics only.
__global__ __launch_bounds__(256) void k_pre(const int* __restrict__ ei,
                                             int* __restrict__ cnt,
                                             int* __restrict__ done,
                                             int* __restrict__ bstart,
                                             int* __restrict__ gcursor,
                                             const float* __restrict__ czw, const float* __restrict__ czb,
                                             const float* __restrict__ lzw, const float* __restrict__ lzb,
                                             const float* __restrict__ chw, const float* __restrict__ chb,
                                             const float* __restrict__ lhw, const float* __restrict__ lhb,
                                             const float* __restrict__ att, float* __restrict__ P) {
    __shared__ int h[NB];
    __shared__ int lastFlag;
    int b = blockIdx.x, t = threadIdx.x;
    for (int j = t; j < NB; j += 256) h[j] = 0;
    __syncthreads();
    const int EPB = NE / 256;  // 6250
    int e0 = b * EPB;
    for (int k = t; k < EPB; k += 256) atomicAdd(&h[ei[NE + e0 + k] >> BSH], 1);
    __syncthreads();
    for (int j = t; j < NB; j += 256) if (h[j]) atomicAdd(&cnt[j], h[j]);
    // ---- last-done block performs the scan + params ----
    if (t == 0) {
        __threadfence();
        int r = atomicAdd(done, 1);
        lastFlag = (r == (int)gridDim.x - 1);
    }
    __syncthreads();
    if (!lastFlag) return;
    // each thread owns 2 consecutive buckets (512 >= 391)
    int j0 = 2 * t;
    int c0 = 0, c1 = 0;
    if (j0 < NB)     c0 = atomicAdd(&cnt[j0], 0);      // device-scope load (skip stale L1)
    if (j0 + 1 < NB) c1 = atomicAdd(&cnt[j0 + 1], 0);
    int s = c0 + c1;
    __syncthreads();           // h[] reuse as scan buffer
    h[t] = s;
    __syncthreads();
    for (int o = 1; o < 256; o <<= 1) {
        int add = (t >= o) ? h[t - o] : 0;
        __syncthreads();
        h[t] += add;
        __syncthreads();
    }
    int e = h[t] - s;  // exclusive prefix over thread-pairs
    if (j0 < NB)     { bstart[j0] = e;     gcursor[j0 * GCS] = e; }
    e += c0;
    if (j0 + 1 < NB) { bstart[j0 + 1] = e; gcursor[(j0 + 1) * GCS] = e; }
    if (t == 0) bstart[NB] = NE;
    // ---- gate params (threads 0..31) ----
    if (t < HH) {
        int j = t;
        float az = 0.f, bz = 0.f, ah = 0.f, bh = 0.f;
        for (int k = 0; k < HH; ++k) {
            float lz = lzw[k * HH + j];
            float lh = lhw[k * HH + j];
            az = fmaf(czw[k], lz, az);
            bz = fmaf(czb[k], lz, bz);
            ah = fmaf(chw[k], lh, ah);
            bh = fmaf(chb[k], lh, bh);
        }
        // pre-scale by log2e so the hot loop uses raw v_exp_f32 (2^x)
        P[j]        = az * LOG2E;
        P[HH + j]   = (bz + lzb[j]) * LOG2E;
        P[2*HH + j] = 2.0f * LOG2E * ah;          // tanh(x) = f(2^(2x*log2e))
        P[3*HH + j] = 2.0f * LOG2E * (bh + lhb[j]);
    }
    if (t == 0) {
        float m = -1e30f;
        for (int q = 0; q < TT; ++q) m = fmaxf(m, att[q]);
        float ex[TT]; float ssum = 0.f;
        for (int q = 0; q < TT; ++q) { ex[q] = expf(att[q] - m); ssum += ex[q]; }
        for (int q = 0; q < TT; ++q) P[4*HH + q] = ex[q] / ssum;
    }
}

// Chunk-local counting sort: bin 4096 edges in LDS, reserve per-bucket global
// runs (1 atomic per non-empty bucket), stream out so each cache line is
// written by one wave in one burst. rec.y = raw ew (dinv folded later).
__global__ __launch_bounds__(512) void k_scatter(const int* __restrict__ ei,
                                                 const float* __restrict__ ew,
                                                 int* __restrict__ gcursor,
                                                 int2* __restrict__ rec) {
    __shared__ int2 cbuf[CHUNK];                 // 32 KB
    __shared__ unsigned short bkt[CHUNK];        // 8 KB
    __shared__ int sc[512];
    __shared__ int cnt[NB], off[NB], cur[NB], gb[NB];
    int t = threadIdx.x;
    int base = blockIdx.x * CHUNK;
    int m = min(CHUNK, NE - base);
    for (int j = t; j < NB; j += 512) { cnt[j] = 0; cur[j] = 0; }
    __syncthreads();
    int dsts[8], srcs[8]; float ews[8];
#pragma unroll
    for (int i = 0; i < 8; ++i) {
        int k = t + i * 512;
        if (k < m) {
            int e = base + k;
            dsts[i] = ei[NE + e]; srcs[i] = ei[e]; ews[i] = ew[e];
            atomicAdd(&cnt[dsts[i] >> BSH], 1);
        }
    }
    __syncthreads();
    int v = (t < NB) ? cnt[t] : 0;
    sc[t] = v;
    __syncthreads();
    for (int o = 1; o < 512; o <<= 1) {
        int add = (t >= o) ? sc[t - o] : 0;
        __syncthreads();
        sc[t] += add;
        __syncthreads();
    }
    if (t < NB) {
        off[t] = sc[t] - v;
        gb[t] = v ? atomicAdd(&gcursor[t * GCS], v) : 0;
    }
    __syncthreads();
#pragma unroll
    for (int i = 0; i < 8; ++i) {
        int k = t + i * 512;
        if (k < m) {
            int b = dsts[i] >> BSH;
            int p = off[b] + atomicAdd(&cur[b], 1);
            // src in bits 0..16 (100000 < 2^17), node-local dst (d&255) in 17..24
            cbuf[p] = make_int2(srcs[i] | ((dsts[i] & 255) << 17), __float_as_int(ews[i]));
            bkt[p] = (unsigned short)b;
        }
    }
    __syncthreads();
    for (int k = t; k < m; k += 512) {
        int b = bkt[k];
        rec[gb[b] + (k - off[b])] = cbuf[k];
    }
}

// One block = one coarse bucket = 256 nodes. In-place sort to exact per-node
// order; computes dinv + nodebase via LDS atomics; pre-scales weight by
// dinv[dst]; ALSO builds the padded pre-scaled feature table
// xp[n][16] = dinv[n] * x[n][0..11] (one aligned 64B line per node) so
// k_fused's gather is a single line with dinv[src] already folded in.
__global__ __launch_bounds__(512) void k_sort(const int* __restrict__ bstart,
                                              int2* __restrict__ rec,
                                              int* __restrict__ nodebase,
                                              float* __restrict__ dinv,
                                              const float* __restrict__ x,
                                              float* __restrict__ xp) {
    __shared__ int2 buf[SORTCAP];                // 37.5 KB
    __shared__ int cnt[256], cur[256], sc[512];
    __shared__ float wsum[256], dvs[256];
    int blk = blockIdx.x, t = threadIdx.x;
    int g0 = bstart[blk], g1 = bstart[blk + 1];
    int m = min(g1 - g0, SORTCAP);
    if (t < 256) { cnt[t] = 0; wsum[t] = 0.f; }
    __syncthreads();
    for (int k = t; k < m; k += 512) {
        int2 r = rec[g0 + k];
        buf[k] = r;
        int loc = (r.x >> 17) & 255;
        atomicAdd(&cnt[loc], 1);
        atomicAdd(&wsum[loc], __int_as_float(r.y));
    }
    __syncthreads();
    int v = (t < 256) ? cnt[t] : 0;
    sc[t] = v;
    __syncthreads();
    for (int o = 1; o < 256; o <<= 1) {
        int add = (t >= o) ? sc[t - o] : 0;
        __syncthreads();
        sc[t] += add;
        __syncthreads();
    }
    if (t < 256) {
        int e = sc[t] - v;  // exclusive prefix
        cur[t] = e;
        float dv = rsqrtf(1.0f + wsum[t]);  // +1 = self loop
        dvs[t] = dv;
        int n = (blk << BSH) + t;
        if (n < NN) {
            dinv[n] = dv; nodebase[n] = g0 + e;
            // build padded pre-scaled feature line
            const float4* xr = (const float4*)(x + (long)n * TT);
            float4* xo = (float4*)(xp + ((long)n << 4));
            float4 v0 = xr[0], v1 = xr[1], v2 = xr[2];
            v0.x *= dv; v0.y *= dv; v0.z *= dv; v0.w *= dv;
            v1.x *= dv; v1.y *= dv; v1.z *= dv; v1.w *= dv;
            v2.x *= dv; v2.y *= dv; v2.z *= dv; v2.w *= dv;
            xo[0] = v0; xo[1] = v1; xo[2] = v2;
        }
    }
    if (blk == NB - 1 && t == 0) nodebase[NN] = NE;
    __syncthreads();
    for (int k = t; k < m; k += 512) {
        int2 r = buf[k];
        int loc = (r.x >> 17) & 255;
        int p = atomicAdd(&cur[loc], 1);
        float w2 = __int_as_float(r.y) * dvs[loc];  // fold dinv[dst] into weight
        rec[g0 + p] = make_int2(r.x & 0x1FFFF, __float_as_int(w2));
    }
}

// 8 lanes per node (coalesced rec reads, 3-level shfl_xor reduce).
// Inner loop per edge: 8B coalesced rec + ONE aligned 64B line from xp
// (dinv[src] pre-folded) -> 72B of line traffic vs 184B before (x rows were
// 48B unaligned = 1.75 lines, plus a dinv line). k_fused was pinned at 42us
// across two configs with different VALU load/occupancy -> gather-line
// throughput is the wall; this cuts it 2.6x.
__global__ __launch_bounds__(512) void k_fused(const int* __restrict__ nodebase,
                                               const int2* __restrict__ rec,
                                               const float* __restrict__ dinv,
                                               const float* __restrict__ xp,
                                               const float* __restrict__ P,
                                               const float* __restrict__ hw,
                                               const float* __restrict__ hb,
                                               float* __restrict__ out) {
    int g = blockIdx.x * 512 + threadIdx.x;
    int n = g >> 3, sub = g & 7;
    if (n >= NN) return;
    float a[TT];
#pragma unroll
    for (int q = 0; q < TT; ++q) a[q] = 0.f;
    if (sub == 0) {
        float di = dinv[n];   // self term = dinv^2 * x = dinv * xp
        const float4* xr = (const float4*)(xp + ((long)n << 4));
#pragma unroll
        for (int q = 0; q < 3; ++q) {
            float4 v = xr[q];
            a[q*4+0] = di * v.x; a[q*4+1] = di * v.y;
            a[q*4+2] = di * v.z; a[q*4+3] = di * v.w;
        }
    }
    int k0 = nodebase[n], k1 = nodebase[n + 1];
    for (int k = k0 + sub; k < k1; k += 8) {
        int2 r = rec[k];
        float c = __int_as_float(r.y);  // = ew * dinv[dst]; dinv[src] is in xp
        const float4* xs = (const float4*)(xp + ((long)r.x << 4));
        float4 v0 = xs[0], v1 = xs[1], v2 = xs[2];
        a[0]  = fmaf(c, v0.x, a[0]);  a[1]  = fmaf(c, v0.y, a[1]);
        a[2]  = fmaf(c, v0.z, a[2]);  a[3]  = fmaf(c, v0.w, a[3]);
        a[4]  = fmaf(c, v1.x, a[4]);  a[5]  = fmaf(c, v1.y, a[5]);
        a[6]  = fmaf(c, v1.z, a[6]);  a[7]  = fmaf(c, v1.w, a[7]);
        a[8]  = fmaf(c, v2.x, a[8]);  a[9]  = fmaf(c, v2.y, a[9]);
        a[10] = fmaf(c, v2.z, a[10]); a[11] = fmaf(c, v2.w, a[11]);
    }
    // tree-reduce the 12 accumulators across the 8 lanes of this node
#pragma unroll
    for (int q = 0; q < TT; ++q) {
        float v = a[q];
        v += __shfl_xor(v, 1);
        v += __shfl_xor(v, 2);
        v += __shfl_xor(v, 4);
        a[q] = v;
    }
    // --- epilogue: gates + attention + head, 4 hidden channels per lane ---
    float p[TT];
#pragma unroll
    for (int q = 0; q < TT; ++q) p[q] = P[4*HH + q];
    float o = 0.f;
#pragma unroll
    for (int jj = 0; jj < 4; ++jj) {
        int j = (jj << 3) + sub;
        float Az = P[j], Bz = P[HH + j], Ah2 = P[2*HH + j], Bh2 = P[3*HH + j];
        float w = hw[j];
        float acc = 0.f;
#pragma unroll
        for (int q = 0; q < TT; ++q) {
            float xz = fmaf(a[q], Az, Bz);                   // log2-domain
            float xh = fminf(fmaf(a[q], Ah2, Bh2), 115.f);   // keep eh finite
            float ez = __builtin_amdgcn_exp2f(xz);  // e^orig_xz
            float eh = __builtin_amdgcn_exp2f(xh);  // e^(2*orig_xh)
            float den = (1.f + ez) * (eh + 1.f);
            float num = eh - 1.f;
            acc = fmaf(p[q] * num, __builtin_amdgcn_rcpf(den), acc);
        }
        o = fmaf(fmaxf(acc, 0.f), w, o);
    }
    o += __shfl_xor(o, 1);
    o += __shfl_xor(o, 2);
    o += __shfl_xor(o, 4);
    if (sub == 0) out[n] = o + hb[0];
}

extern "C" void kernel_launch(void* const* d_in, const int* in_sizes, int n_in,
                              void* d_out, int out_size, void* d_ws, size_t ws_size,
                              hipStream_t stream) {
    const float* x    = (const float*)d_in[0];
    const int*   ei   = (const int*)d_in[1];
    const float* ew   = (const float*)d_in[2];
    const float* att  = (const float*)d_in[3];
    const float* czw  = (const float*)d_in[4];
    const float* czb  = (const float*)d_in[5];
    const float* lzw  = (const float*)d_in[6];
    const float* lzb  = (const float*)d_in[7];
    // conv_r / lin_r (d_in[8..11]) are mathematically dead: H=0 -> H*R=0, Z*H=0.
    const float* chw  = (const float*)d_in[12];
    const float* chb  = (const float*)d_in[13];
    const float* lhw  = (const float*)d_in[14];
    const float* lhb  = (const float*)d_in[15];
    const float* hw   = (const float*)d_in[16];
    const float* hb   = (const float*)d_in[17];
    float* out = (float*)d_out;

    int*  ws32     = (int*)d_ws;
    int*  bstart   = ws32;                     // 392 (pad to 400)
    int*  cnt      = ws32 + 400;               // 391 (pad to 400)
    int*  done     = ws32 + 800;               // 1 (pad to 16)
    int*  gcursor  = ws32 + 816;               // NB*GCS = 6256
    int*  nodebase = ws32 + 7072;              // 100001 (pad to 100016)
    float* dinv    = (float*)(ws32 + 107088);  // NN (pad to 207104 = 16-aligned)
    float* xp      = (float*)(ws32 + 207104);  // NN*16 floats, 64B-aligned rows
    int2* rec      = (int2*)(ws32 + 1807104);  // NE int2; byte off 7228416 % 8 == 0
    float* P       = (float*)(ws32 + 5007104); // 144

    hipMemsetAsync(ws32 + 400, 0, (size_t)(816 - 400) * 4, stream);  // cnt + done
    k_pre<<<256, 256, 0, stream>>>(ei, cnt, done, bstart, gcursor,
                                   czw, czb, lzw, lzb, chw, chb, lhw, lhb, att, P);
    k_scatter<<<(NE + CHUNK - 1) / CHUNK, 512, 0, stream>>>(ei, ew, gcursor, rec);
    k_sort<<<NB, 512, 0, stream>>>(bstart, rec, nodebase, dinv, x, xp);
    k_fused<<<(NN * 8 + 511) / 512, 512, 0, stream>>>(nodebase, rec, dinv, xp, P, hw, hb, out);
}

// Round 5
// 98.982 us; speedup vs baseline: 1.7447x; 1.0130x over previous
//
#include <hip/hip_runtime.h>

#define NN 100000
#define NE 1600000
#define TT 12
#define HH 32
#define NB 391          // coarse buckets of 256 nodes (node bucket = d >> 8)
#define BSH 8
#define GCS 16          // gcursor stride (ints) = one 64B line per cursor
#define CHUNK 4096      // edges per scatter block
#define SORTCAP 4800    // records per sort block (mean 4096, sigma 64 -> +11 sigma)
#define LOG2E 1.4426950408889634f

// ---------------- workspace layout (4-byte units), ~20.0 MB ----------------
// [0, 400)             : bstart[392]
// [400, 800)           : cnt[391]      (zeroed by k_zero)
// [800, 816)           : done flag     (zeroed by k_zero)
// [816, 7072)          : gcursor (x16 padded)
// [7072, 107088)       : nodebase[100001]
// [107088, 207088)     : dinv (float)
// [207104, 1807104)    : xp (float[NN][16]) = dinv[n]*x[n], 64B-aligned rows
// [1807104, 5007104)   : rec (int2[NE]); byte off 7228416 % 8 == 0
// [5007104, 5007248)   : P params: Az[32],Bz[32],Ah2[32],Bh2[32],probs[12]
//                        (gate params pre-scaled by log2e for raw v_exp_f32)

// R4 lesson: hipMemsetAsync becomes __amd_rocclr_fillBufferAligned which
// measured 42-43us for a 1.6KB fill (launch/drain-bound blit kernel, 8%
// occupancy). A 1-block zero kernel does the same work in ~2us.
__global__ __launch_bounds__(512) void k_zero(int* __restrict__ ws32) {
    int t = threadIdx.x;
    if (t < 416) ws32[400 + t] = 0;   // cnt[391] + pad + done
}

// Bucket histogram; the LAST block to finish (global done counter) then does
// the bucket scan + gate-param folding in the same launch.
// NOTE: per-edge GLOBAL float atomics are catastrophic on gfx950 (R2: 90us,
// WRITE_SIZE == 1.6M x 32B -> uncached fabric writes). LDS atomics only.
__global__ __launch_bounds__(256) void k_pre(const int* __restrict__ ei,
                                             int* __restrict__ cnt,
                                             int* __restrict__ done,
                                             int* __restrict__ bstart,
                                             int* __restrict__ gcursor,
                                             const float* __restrict__ czw, const float* __restrict__ czb,
                                             const float* __restrict__ lzw, const float* __restrict__ lzb,
                                             const float* __restrict__ chw, const float* __restrict__ chb,
                                             const float* __restrict__ lhw, const float* __restrict__ lhb,
                                             const float* __restrict__ att, float* __restrict__ P) {
    __shared__ int h[NB];
    __shared__ int lastFlag;
    int b = blockIdx.x, t = threadIdx.x;
    for (int j = t; j < NB; j += 256) h[j] = 0;
    __syncthreads();
    const int EPB = NE / 256;  // 6250
    int e0 = b * EPB;
    for (int k = t; k < EPB; k += 256) atomicAdd(&h[ei[NE + e0 + k] >> BSH], 1);
    __syncthreads();
    for (int j = t; j < NB; j += 256) if (h[j]) atomicAdd(&cnt[j], h[j]);
    // ---- last-done block performs the scan + params ----
    if (t == 0) {
        __threadfence();
        int r = atomicAdd(done, 1);
        lastFlag = (r == (int)gridDim.x - 1);
    }
    __syncthreads();
    if (!lastFlag) return;
    // each thread owns 2 consecutive buckets (512 >= 391)
    int j0 = 2 * t;
    int c0 = 0, c1 = 0;
    if (j0 < NB)     c0 = atomicAdd(&cnt[j0], 0);      // device-scope load (skip stale L1)
    if (j0 + 1 < NB) c1 = atomicAdd(&cnt[j0 + 1], 0);
    int s = c0 + c1;
    __syncthreads();           // h[] reuse as scan buffer
    h[t] = s;
    __syncthreads();
    for (int o = 1; o < 256; o <<= 1) {
        int add = (t >= o) ? h[t - o] : 0;
        __syncthreads();
        h[t] += add;
        __syncthreads();
    }
    int e = h[t] - s;  // exclusive prefix over thread-pairs
    if (j0 < NB)     { bstart[j0] = e;     gcursor[j0 * GCS] = e; }
    e += c0;
    if (j0 + 1 < NB) { bstart[j0 + 1] = e; gcursor[(j0 + 1) * GCS] = e; }
    if (t == 0) bstart[NB] = NE;
    // ---- gate params (threads 0..31) ----
    if (t < HH) {
        int j = t;
        float az = 0.f, bz = 0.f, ah = 0.f, bh = 0.f;
        for (int k = 0; k < HH; ++k) {
            float lz = lzw[k * HH + j];
            float lh = lhw[k * HH + j];
            az = fmaf(czw[k], lz, az);
            bz = fmaf(czb[k], lz, bz);
            ah = fmaf(chw[k], lh, ah);
            bh = fmaf(chb[k], lh, bh);
        }
        // pre-scale by log2e so the hot loop uses raw v_exp_f32 (2^x)
        P[j]        = az * LOG2E;
        P[HH + j]   = (bz + lzb[j]) * LOG2E;
        P[2*HH + j] = 2.0f * LOG2E * ah;          // tanh(x) = f(2^(2x*log2e))
        P[3*HH + j] = 2.0f * LOG2E * (bh + lhb[j]);
    }
    if (t == 0) {
        float m = -1e30f;
        for (int q = 0; q < TT; ++q) m = fmaxf(m, att[q]);
        float ex[TT]; float ssum = 0.f;
        for (int q = 0; q < TT; ++q) { ex[q] = expf(att[q] - m); ssum += ex[q]; }
        for (int q = 0; q < TT; ++q) P[4*HH + q] = ex[q] / ssum;
    }
}

// Chunk-local counting sort: bin 4096 edges in LDS, reserve per-bucket global
// runs (1 atomic per non-empty bucket), stream out so each cache line is
// written by one wave in one burst. rec.y = raw ew (dinv folded later).
__global__ __launch_bounds__(512) void k_scatter(const int* __restrict__ ei,
                                                 const float* __restrict__ ew,
                                                 int* __restrict__ gcursor,
                                                 int2* __restrict__ rec) {
    __shared__ int2 cbuf[CHUNK];                 // 32 KB
    __shared__ unsigned short bkt[CHUNK];        // 8 KB
    __shared__ int sc[512];
    __shared__ int cnt[NB], off[NB], cur[NB], gb[NB];
    int t = threadIdx.x;
    int base = blockIdx.x * CHUNK;
    int m = min(CHUNK, NE - base);
    for (int j = t; j < NB; j += 512) { cnt[j] = 0; cur[j] = 0; }
    __syncthreads();
    int dsts[8], srcs[8]; float ews[8];
#pragma unroll
    for (int i = 0; i < 8; ++i) {
        int k = t + i * 512;
        if (k < m) {
            int e = base + k;
            dsts[i] = ei[NE + e]; srcs[i] = ei[e]; ews[i] = ew[e];
            atomicAdd(&cnt[dsts[i] >> BSH], 1);
        }
    }
    __syncthreads();
    int v = (t < NB) ? cnt[t] : 0;
    sc[t] = v;
    __syncthreads();
    for (int o = 1; o < 512; o <<= 1) {
        int add = (t >= o) ? sc[t - o] : 0;
        __syncthreads();
        sc[t] += add;
        __syncthreads();
    }
    if (t < NB) {
        off[t] = sc[t] - v;
        gb[t] = v ? atomicAdd(&gcursor[t * GCS], v) : 0;
    }
    __syncthreads();
#pragma unroll
    for (int i = 0; i < 8; ++i) {
        int k = t + i * 512;
        if (k < m) {
            int b = dsts[i] >> BSH;
            int p = off[b] + atomicAdd(&cur[b], 1);
            // src in bits 0..16 (100000 < 2^17), node-local dst (d&255) in 17..24
            cbuf[p] = make_int2(srcs[i] | ((dsts[i] & 255) << 17), __float_as_int(ews[i]));
            bkt[p] = (unsigned short)b;
        }
    }
    __syncthreads();
    for (int k = t; k < m; k += 512) {
        int b = bkt[k];
        rec[gb[b] + (k - off[b])] = cbuf[k];
    }
}

// One block = one coarse bucket = 256 nodes. In-place sort to exact per-node
// order; computes dinv + nodebase via LDS atomics; pre-scales weight by
// dinv[dst]; ALSO builds the padded pre-scaled feature table
// xp[n][16] = dinv[n] * x[n][0..11] (one aligned 64B line per node) so
// k_fused's gather is a single line with dinv[src] already folded in.
__global__ __launch_bounds__(512) void k_sort(const int* __restrict__ bstart,
                                              int2* __restrict__ rec,
                                              int* __restrict__ nodebase,
                                              float* __restrict__ dinv,
                                              const float* __restrict__ x,
                                              float* __restrict__ xp) {
    __shared__ int2 buf[SORTCAP];                // 37.5 KB
    __shared__ int cnt[256], cur[256], sc[512];
    __shared__ float wsum[256], dvs[256];
    int blk = blockIdx.x, t = threadIdx.x;
    int g0 = bstart[blk], g1 = bstart[blk + 1];
    int m = min(g1 - g0, SORTCAP);
    if (t < 256) { cnt[t] = 0; wsum[t] = 0.f; }
    __syncthreads();
    for (int k = t; k < m; k += 512) {
        int2 r = rec[g0 + k];
        buf[k] = r;
        int loc = (r.x >> 17) & 255;
        atomicAdd(&cnt[loc], 1);
        atomicAdd(&wsum[loc], __int_as_float(r.y));
    }
    __syncthreads();
    int v = (t < 256) ? cnt[t] : 0;
    sc[t] = v;
    __syncthreads();
    for (int o = 1; o < 256; o <<= 1) {
        int add = (t >= o) ? sc[t - o] : 0;
        __syncthreads();
        sc[t] += add;
        __syncthreads();
    }
    if (t < 256) {
        int e = sc[t] - v;  // exclusive prefix
        cur[t] = e;
        float dv = rsqrtf(1.0f + wsum[t]);  // +1 = self loop
        dvs[t] = dv;
        int n = (blk << BSH) + t;
        if (n < NN) {
            dinv[n] = dv; nodebase[n] = g0 + e;
            // build padded pre-scaled feature line
            const float4* xr = (const float4*)(x + (long)n * TT);
            float4* xo = (float4*)(xp + ((long)n << 4));
            float4 v0 = xr[0], v1 = xr[1], v2 = xr[2];
            v0.x *= dv; v0.y *= dv; v0.z *= dv; v0.w *= dv;
            v1.x *= dv; v1.y *= dv; v1.z *= dv; v1.w *= dv;
            v2.x *= dv; v2.y *= dv; v2.z *= dv; v2.w *= dv;
            xo[0] = v0; xo[1] = v1; xo[2] = v2;
        }
    }
    if (blk == NB - 1 && t == 0) nodebase[NN] = NE;
    __syncthreads();
    for (int k = t; k < m; k += 512) {
        int2 r = buf[k];
        int loc = (r.x >> 17) & 255;
        int p = atomicAdd(&cur[loc], 1);
        float w2 = __int_as_float(r.y) * dvs[loc];  // fold dinv[dst] into weight
        rec[g0 + p] = make_int2(r.x & 0x1FFFF, __float_as_int(w2));
    }
}

// 8 lanes per node (coalesced rec reads, 3-level shfl_xor reduce).
// Inner loop per edge: 8B coalesced rec + ONE aligned 64B line from xp
// (dinv[src] pre-folded) -> 72B of line traffic vs 184B before.
__global__ __launch_bounds__(512) void k_fused(const int* __restrict__ nodebase,
                                               const int2* __restrict__ rec,
                                               const float* __restrict__ dinv,
                                               const float* __restrict__ xp,
                                               const float* __restrict__ P,
                                               const float* __restrict__ hw,
                                               const float* __restrict__ hb,
                                               float* __restrict__ out) {
    int g = blockIdx.x * 512 + threadIdx.x;
    int n = g >> 3, sub = g & 7;
    if (n >= NN) return;
    float a[TT];
#pragma unroll
    for (int q = 0; q < TT; ++q) a[q] = 0.f;
    if (sub == 0) {
        float di = dinv[n];   // self term = dinv^2 * x = dinv * xp
        const float4* xr = (const float4*)(xp + ((long)n << 4));
#pragma unroll
        for (int q = 0; q < 3; ++q) {
            float4 v = xr[q];
            a[q*4+0] = di * v.x; a[q*4+1] = di * v.y;
            a[q*4+2] = di * v.z; a[q*4+3] = di * v.w;
        }
    }
    int k0 = nodebase[n], k1 = nodebase[n + 1];
    for (int k = k0 + sub; k < k1; k += 8) {
        int2 r = rec[k];
        float c = __int_as_float(r.y);  // = ew * dinv[dst]; dinv[src] is in xp
        const float4* xs = (const float4*)(xp + ((long)r.x << 4));
        float4 v0 = xs[0], v1 = xs[1], v2 = xs[2];
        a[0]  = fmaf(c, v0.x, a[0]);  a[1]  = fmaf(c, v0.y, a[1]);
        a[2]  = fmaf(c, v0.z, a[2]);  a[3]  = fmaf(c, v0.w, a[3]);
        a[4]  = fmaf(c, v1.x, a[4]);  a[5]  = fmaf(c, v1.y, a[5]);
        a[6]  = fmaf(c, v1.z, a[6]);  a[7]  = fmaf(c, v1.w, a[7]);
        a[8]  = fmaf(c, v2.x, a[8]);  a[9]  = fmaf(c, v2.y, a[9]);
        a[10] = fmaf(c, v2.z, a[10]); a[11] = fmaf(c, v2.w, a[11]);
    }
    // tree-reduce the 12 accumulators across the 8 lanes of this node
#pragma unroll
    for (int q = 0; q < TT; ++q) {
        float v = a[q];
        v += __shfl_xor(v, 1);
        v += __shfl_xor(v, 2);
        v += __shfl_xor(v, 4);
        a[q] = v;
    }
    // --- epilogue: gates + attention + head, 4 hidden channels per lane ---
    float p[TT];
#pragma unroll
    for (int q = 0; q < TT; ++q) p[q] = P[4*HH + q];
    float o = 0.f;
#pragma unroll
    for (int jj = 0; jj < 4; ++jj) {
        int j = (jj << 3) + sub;
        float Az = P[j], Bz = P[HH + j], Ah2 = P[2*HH + j], Bh2 = P[3*HH + j];
        float w = hw[j];
        float acc = 0.f;
#pragma unroll
        for (int q = 0; q < TT; ++q) {
            float xz = fmaf(a[q], Az, Bz);                   // log2-domain
            float xh = fminf(fmaf(a[q], Ah2, Bh2), 115.f);   // keep eh finite
            float ez = __builtin_amdgcn_exp2f(xz);  // e^orig_xz
            float eh = __builtin_amdgcn_exp2f(xh);  // e^(2*orig_xh)
            float den = (1.f + ez) * (eh + 1.f);
            float num = eh - 1.f;
            acc = fmaf(p[q] * num, __builtin_amdgcn_rcpf(den), acc);
        }
        o = fmaf(fmaxf(acc, 0.f), w, o);
    }
    o += __shfl_xor(o, 1);
    o += __shfl_xor(o, 2);
    o += __shfl_xor(o, 4);
    if (sub == 0) out[n] = o + hb[0];
}

extern "C" void kernel_launch(void* const* d_in, const int* in_sizes, int n_in,
                              void* d_out, int out_size, void* d_ws, size_t ws_size,
                              hipStream_t stream) {
    const float* x    = (const float*)d_in[0];
    const int*   ei   = (const int*)d_in[1];
    const float* ew   = (const float*)d_in[2];
    const float* att  = (const float*)d_in[3];
    const float* czw  = (const float*)d_in[4];
    const float* czb  = (const float*)d_in[5];
    const float* lzw  = (const float*)d_in[6];
    const float* lzb  = (const float*)d_in[7];
    // conv_r / lin_r (d_in[8..11]) are mathematically dead: H=0 -> H*R=0, Z*H=0.
    const float* chw  = (const float*)d_in[12];
    const float* chb  = (const float*)d_in[13];
    const float* lhw  = (const float*)d_in[14];
    const float* lhb  = (const float*)d_in[15];
    const float* hw   = (const float*)d_in[16];
    const float* hb   = (const float*)d_in[17];
    float* out = (float*)d_out;

    int*  ws32     = (int*)d_ws;
    int*  bstart   = ws32;                     // 392 (pad to 400)
    int*  cnt      = ws32 + 400;               // 391 (pad to 400)
    int*  done     = ws32 + 800;               // 1 (pad to 16)
    int*  gcursor  = ws32 + 816;               // NB*GCS = 6256
    int*  nodebase = ws32 + 7072;              // 100001 (pad to 100016)
    float* dinv    = (float*)(ws32 + 107088);  // NN (pad to 207104 = 16-aligned)
    float* xp      = (float*)(ws32 + 207104);  // NN*16 floats, 64B-aligned rows
    int2* rec      = (int2*)(ws32 + 1807104);  // NE int2; byte off 7228416 % 8 == 0
    float* P       = (float*)(ws32 + 5007104); // 144

    k_zero<<<1, 512, 0, stream>>>(ws32);
    k_pre<<<256, 256, 0, stream>>>(ei, cnt, done, bstart, gcursor,
                                   czw, czb, lzw, lzb, chw, chb, lhw, lhb, att, P);
    k_scatter<<<(NE + CHUNK - 1) / CHUNK, 512, 0, stream>>>(ei, ew, gcursor, rec);
    k_sort<<<NB, 512, 0, stream>>>(bstart, rec, nodebase, dinv, x, xp);
    k_fused<<<(NN * 8 + 511) / 512, 512, 0, stream>>>(nodebase, rec, dinv, xp, P, hw, hb, out);
}